// Round 1
// baseline (781.817 us; speedup 1.0000x reference)
//
#include <hip/hip_runtime.h>

#define TZ 8
#define TH 8
#define TW 16
#define PZ (TZ + 2)   // 10
#define PH (TH + 2)   // 10
#define PW (TW + 2)   // 18
#define PWS 19        // LDS row stride (pad to odd to break bank pattern)
#define NTHREADS 512

__global__ __launch_bounds__(NTHREADS)
void wincorr_kernel(const float* __restrict__ x, const float* __restrict__ y,
                    float* __restrict__ out)
{
    __shared__ float ytile[PZ][PH][PWS];

    const int C = 64;
    const long long plane = 512000;   // 80*80*80

    const int tid = threadIdx.x;
    const int tw = tid & 7;          // 0..7  (w pair index)
    const int th = (tid >> 3) & 7;   // 0..7
    const int tz = tid >> 6;         // 0..7

    const int wt = blockIdx.x;           // 0..4
    const int ht = blockIdx.y % 10;      // 0..9
    const int zt = blockIdx.y / 10;      // 0..9
    const int b  = blockIdx.z;           // 0..1

    const int z0 = zt * TZ, h0 = ht * TH, w0 = wt * TW;
    const int gz = z0 + tz, gh = h0 + th, gw = w0 + 2 * tw;

    float acc[27][2];
#pragma unroll
    for (int i = 0; i < 27; ++i) { acc[i][0] = 0.f; acc[i][1] = 0.f; }

    const float* xb = x + (long long)b * C * plane;
    const float* yb = y + (long long)b * C * plane;
    const long long sp_off = (long long)gz * 6400 + gh * 80 + gw;

    for (int c = 0; c < C; ++c) {
        // x pair for this thread's two outputs (read exactly once)
        const float2 xv = *(const float2*)(xb + (long long)c * plane + sp_off);
        const float x0 = xv.x, x1 = xv.y;

        __syncthreads();   // previous iteration's LDS reads done
        // stage padded y tile: 10*10*18 = 1800 elements
        const float* yc = yb + (long long)c * plane;
        for (int idx = tid; idx < PZ * PH * PW; idx += NTHREADS) {
            int px  = idx % PW;
            int rem = idx / PW;
            int py  = rem % PH;
            int pz  = rem / PH;
            int yz = z0 - 1 + pz, yh = h0 - 1 + py, yw = w0 - 1 + px;
            float v = 0.f;
            if ((unsigned)yz < 80u && (unsigned)yh < 80u && (unsigned)yw < 80u)
                v = yc[yz * 6400 + yh * 80 + yw];
            ytile[pz][py][px] = v;
        }
        __syncthreads();

#pragma unroll
        for (int dz = 0; dz < 3; ++dz) {
#pragma unroll
            for (int dy = 0; dy < 3; ++dy) {
                const float* row = &ytile[tz + dz][th + dy][2 * tw];
                const float r0 = row[0], r1 = row[1], r2 = row[2], r3 = row[3];
                const int o = (dz * 3 + dy) * 3;
                acc[o + 0][0] += x0 * r0; acc[o + 0][1] += x1 * r1;
                acc[o + 1][0] += x0 * r1; acc[o + 1][1] += x1 * r2;
                acc[o + 2][0] += x0 * r2; acc[o + 2][1] += x1 * r3;
            }
        }
    }

    // epilogue: out[b][o][gz][gh][gw..gw+1], scale by 64^-0.5 = 0.125
    float* ob = out + (long long)b * 27 * plane + sp_off;
#pragma unroll
    for (int o = 0; o < 27; ++o) {
        float2 v = make_float2(acc[o][0] * 0.125f, acc[o][1] * 0.125f);
        *(float2*)(ob + (long long)o * plane) = v;
    }
}

extern "C" void kernel_launch(void* const* d_in, const int* in_sizes, int n_in,
                              void* d_out, int out_size, void* d_ws, size_t ws_size,
                              hipStream_t stream) {
    const float* x = (const float*)d_in[0];
    const float* y = (const float*)d_in[1];
    float* out = (float*)d_out;

    dim3 grid(80 / TW, (80 / TH) * (80 / TZ), 2);  // (5, 100, 2)
    dim3 block(NTHREADS);
    wincorr_kernel<<<grid, block, 0, stream>>>(x, y, out);
}

// Round 2
// 750.373 us; speedup vs baseline: 1.0419x; 1.0419x over previous
//
#include <hip/hip_runtime.h>

#define NT 320          // threads/block (5 waves)
#define TZ 4
#define TH 4
#define PZ 6            // TZ+2
#define PH 6            // TH+2
#define STR 88          // LDS row stride in floats (mult of 4 for b128 alignment)
#define PROWS (PZ*PH)   // 36 rows per channel tile
#define NSLOT (PROWS*20)// 720 float4 staging slots per channel

__global__ __launch_bounds__(NT)
void wincorr_kernel(const float* __restrict__ x, const float* __restrict__ y,
                    float* __restrict__ out)
{
    __shared__ __align__(16) float buf[2][PROWS * STR];

    const long long plane = 512000;  // 80*80*80
    const int tid = threadIdx.x;
    const int twi = tid % 20;        // float4 column within row (w = 4*twi)
    const int th  = (tid / 20) % TH;
    const int tz  = tid / 80;

    const int zt = blockIdx.x, ht = blockIdx.y, b = blockIdx.z;
    const int z0 = zt * TZ, h0 = ht * TH;
    const int gz = z0 + tz, gh = h0 + th, wb = 4 * twi;

    const float* xb = x + (long long)b * 64 * plane;
    const float* yb = y + (long long)b * 64 * plane;
    const long long xoff = (long long)gz * 6400 + gh * 80 + wb;

    // ---- staging precompute: 3 float4 slots per thread ----
    int  goff[3], loff[3];
    bool val[3];
    const bool inr2 = (tid + 2 * NT) < NSLOT;   // k=0,1 always in range
#pragma unroll
    for (int k = 0; k < 3; ++k) {
        int s   = tid + k * NT;
        int row = s / 20, col = s % 20;
        int pz = row / PH, py = row % PH;
        int yz = z0 - 1 + pz, yh = h0 - 1 + py;
        bool ok = (s < NSLOT) && ((unsigned)yz < 80u) && ((unsigned)yh < 80u);
        val[k]  = ok;
        goff[k] = yz * 6400 + yh * 80 + 4 * col;
        loff[k] = row * STR + 4 + 4 * col;
    }

    // w-halo zeros (idx 3 => w=-1, idx 84 => w=80), written once, both buffers.
    if (tid < 2 * PROWS) {
        int r = tid >> 1;
        int cix = (tid & 1) ? 84 : 3;
        buf[0][r * STR + cix] = 0.f;
        buf[1][r * STR + cix] = 0.f;
    }

    float4 acc[27];
#pragma unroll
    for (int o = 0; o < 27; ++o) acc[o] = make_float4(0.f, 0.f, 0.f, 0.f);

    const float4 zero4 = make_float4(0.f, 0.f, 0.f, 0.f);
    float4 v0, v1, v2;

    // preload channel 0
    {
        const float* yc = yb;
        v0 = val[0] ? *(const float4*)(yc + goff[0]) : zero4;
        v1 = val[1] ? *(const float4*)(yc + goff[1]) : zero4;
        v2 = val[2] ? *(const float4*)(yc + goff[2]) : zero4;
        *(float4*)(&buf[0][loff[0]]) = v0;
        *(float4*)(&buf[0][loff[1]]) = v1;
        if (inr2) *(float4*)(&buf[0][loff[2]]) = v2;
    }
    __syncthreads();

    for (int c = 0; c < 64; ++c) {
        const float4 xv = *(const float4*)(xb + (long long)c * plane + xoff);

        // issue next channel's global loads (latency overlapped with compute)
        if (c < 63) {
            const float* yc = yb + (long long)(c + 1) * plane;
            v0 = val[0] ? *(const float4*)(yc + goff[0]) : zero4;
            v1 = val[1] ? *(const float4*)(yc + goff[1]) : zero4;
            v2 = val[2] ? *(const float4*)(yc + goff[2]) : zero4;
        }

        const float* B = buf[c & 1];
#pragma unroll
        for (int dz = 0; dz < 3; ++dz) {
#pragma unroll
            for (int dy = 0; dy < 3; ++dy) {
                const float* rowp = B + ((tz + dz) * PH + (th + dy)) * STR + wb;
                const float4 r  = *(const float4*)(rowp + 4);  // y[wb..wb+3]
                const float rm1 = rowp[3];                     // y[wb-1]
                const float rp4 = rowp[8];                     // y[wb+4]
                const int o = (dz * 3 + dy) * 3;
                acc[o].x   += xv.x * rm1; acc[o].y   += xv.y * r.x;
                acc[o].z   += xv.z * r.y; acc[o].w   += xv.w * r.z;
                acc[o+1].x += xv.x * r.x; acc[o+1].y += xv.y * r.y;
                acc[o+1].z += xv.z * r.z; acc[o+1].w += xv.w * r.w;
                acc[o+2].x += xv.x * r.y; acc[o+2].y += xv.y * r.z;
                acc[o+2].z += xv.z * r.w; acc[o+2].w += xv.w * rp4;
            }
        }

        if (c < 63) {
            float* W = (float*)buf[(c + 1) & 1];
            *(float4*)(W + loff[0]) = v0;
            *(float4*)(W + loff[1]) = v1;
            if (inr2) *(float4*)(W + loff[2]) = v2;
        }
        __syncthreads();
    }

    // epilogue: scale by 64^-0.5 = 0.125, coalesced float4 stores
    float* ob = out + (long long)b * 27 * plane + xoff;
#pragma unroll
    for (int o = 0; o < 27; ++o) {
        float4 v = acc[o];
        v.x *= 0.125f; v.y *= 0.125f; v.z *= 0.125f; v.w *= 0.125f;
        *(float4*)(ob + (long long)o * plane) = v;
    }
}

extern "C" void kernel_launch(void* const* d_in, const int* in_sizes, int n_in,
                              void* d_out, int out_size, void* d_ws, size_t ws_size,
                              hipStream_t stream) {
    const float* x = (const float*)d_in[0];
    const float* y = (const float*)d_in[1];
    float* out = (float*)d_out;

    dim3 grid(80 / TZ, 80 / TH, 2);   // (20, 20, 2) = 800 blocks
    dim3 block(NT);
    wincorr_kernel<<<grid, block, 0, stream>>>(x, y, out);
}